// Round 22
// baseline (258.695 us; speedup 1.0000x reference)
//
#include <hip/hip_runtime.h>
#include <hip/hip_bf16.h>

// Problem constants
#define N_ 64
#define C_ 64
#define T_ 300
#define V_ 25
#define K_ 3
#define TT 12             // t-values per tile
#define NTILE 25          // T_/TT
#define NBLK 1600         // total tiles
#define NPERS 800         // blocks; block bid owns tiles 2*bid, 2*bid+1
#define XROW 384          // xs row pitch in elems: TT*32
#define WP 72             // W-lds row pitch (144B, 16B-aligned b128 frag reads)
#define ATP 40            // At-lds row pitch (80B, 16B-aligned b128 frag reads)
#define NTHR 512          // 8 waves: (ob 0..3) x (t-half 0..1)
#define EPS_ 1e-5f

typedef __bf16 bf16_t;
typedef __bf16 bf16x4 __attribute__((ext_vector_type(4)));
typedef __bf16 bf16x8 __attribute__((ext_vector_type(8)));
typedef float f32x4 __attribute__((ext_vector_type(4)));
typedef float f32x4u __attribute__((ext_vector_type(4), aligned(4)));

static __device__ __forceinline__ bf16_t tobf(float f) { return (bf16_t)f; }
// element-index swizzle within a c-row (XOR of bits 3..5: keeps 4-runs contiguous)
static __device__ __forceinline__ int emask(int c) { return ((c & 3) << 3) | ((c & 8) << 2); }

// LDS overlay: W/A staging (prologue only; frags move to registers) reuses xs.
union SmemU {
  struct { bf16_t W[3 * 64 * WP]; bf16_t At[3 * 32 * ATP]; } wa;   // 35.3KB
  bf16_t xs[64 * XROW];                                            // 48KB
};

struct Frags {
  bf16x8 wfrag[6];
  bf16x8 afrag[3][2];
  int fK[4], fS5[4];
  float bs[4];
  int obase;
};

// ---------------------------------------------------------------------------
// K0: warm-up stream. Pull ALL of x (123MB) HBM->L3, no barriers, full MLP.
// Steady state (no-y plan, nt out stores keep L3 clean): all-hit, ~10us.
// ---------------------------------------------------------------------------
__global__ __launch_bounds__(256) void k0_warm(const float* __restrict__ x) {
  const f32x4* xv = reinterpret_cast<const f32x4*>(x);
  f32x4 acc = {0.f, 0.f, 0.f, 0.f};
  for (long i = (long)blockIdx.x * 256 + threadIdx.x; i < 7680000L;
       i += (long)gridDim.x * 256)
    acc += xv[i];
  float s = acc[0] + acc[1] + acc[2] + acc[3];
  asm volatile("" :: "v"(s));   // keep loads alive (rule #17)
}

// ---- coalesced W/A global->LDS staging (bf16)
static __device__ __forceinline__ void stage_wa(
    const float* __restrict__ A, const float* __restrict__ W, SmemU& sm, int tid) {
  for (int m = tid; m < 3072; m += NTHR) {
    f32x4 v4 = *(reinterpret_cast<const f32x4*>(W) + m);
    int f = m << 2;
    int k = f >> 12, o = (f >> 6) & 63, c = f & 63;
    bf16x4 h;
    h[0] = tobf(v4[0]); h[1] = tobf(v4[1]); h[2] = tobf(v4[2]); h[3] = tobf(v4[3]);
    *reinterpret_cast<bf16x4*>(&sm.wa.W[(k * 64 + o) * WP + c]) = h;
  }
  for (int i = tid; i < 3072; i += NTHR) {
    int k = i >> 10, r = i & 1023, w = r >> 5, v = r & 31;
    float val = (v < V_ && w < V_) ? A[k * 625 + v * 25 + w] : 0.f;
    sm.wa.At[(k * 32 + w) * ATP + v] = tobf(val);
  }
}

static __device__ __forceinline__ void read_frags(
    const SmemU& sm, const float* __restrict__ b, int ob, int l15, int lg, Frags& F) {
  const int o = ob * 16 + l15;
  #pragma unroll
  for (int k = 0; k < 3; ++k)
    #pragma unroll
    for (int ch = 0; ch < 2; ++ch)
      F.wfrag[k * 2 + ch] =
          *reinterpret_cast<const bf16x8*>(&sm.wa.W[(k * 64 + o) * WP + ch * 32 + lg * 8]);
  #pragma unroll
  for (int k = 0; k < 3; ++k)
    #pragma unroll
    for (int wh = 0; wh < 2; ++wh)
      F.afrag[k][wh] =
          *reinterpret_cast<const bf16x8*>(&sm.wa.At[(k * 32 + wh * 16 + l15) * ATP + lg * 8]);
  // per-lane fragment LDS offsets. Permuted c-map (R3..R21-verified):
  // frag q=(chalf,sub): c = chalf*32 + sub*4 + 8*(l15>>2) + (l15&3)
  const int crow = 8 * (l15 >> 2) + (l15 & 3);
  #pragma unroll
  for (int q = 0; q < 4; ++q) {
    int c = ((q >> 1) * 32) + ((q & 1) * 4) + crow;
    int em = emask(c);
    F.fK[q] = c * XROW + ((lg * 8) ^ (em & 24));
    F.fS5[q] = em & 32;
  }
  F.obase = ob * 16 + lg * 4;
  #pragma unroll
  for (int r = 0; r < 4; ++r)
    F.bs[r] = b[F.obase + r] + b[64 + F.obase + r] + b[128 + F.obase + r];
}

// ---- x staging: 512 threads = 64 c-rows x 8 v-blocks; pure bit-op indexing.
static __device__ __forceinline__ void stage_x(
    const float* __restrict__ x, SmemU& sm, int n, int t0, int tid) {
  const int c = tid >> 3, vb = tid & 7;
  const int em = emask(c);
  const float* xr = x + (size_t)n * 480000 + (size_t)c * 7500 + (size_t)t0 * 25;
  bf16_t* xsr = &sm.xs[c * XROW];
  #pragma unroll
  for (int t = 0; t < TT; ++t) {
    bf16x4 h;
    if (vb < 6) {
      f32x4u v4 = *reinterpret_cast<const f32x4u*>(xr + t * 25 + vb * 4);
      h[0] = tobf(v4[0]); h[1] = tobf(v4[1]); h[2] = tobf(v4[2]); h[3] = tobf(v4[3]);
    } else if (vb == 6) {
      float s = xr[t * 25 + 24];
      h[0] = tobf(s); h[1] = tobf(0.f); h[2] = tobf(0.f); h[3] = tobf(0.f);
    } else {
      h[0] = tobf(0.f); h[1] = tobf(0.f); h[2] = tobf(0.f); h[3] = tobf(0.f);
    }
    *reinterpret_cast<bf16x4*>(&xsr[(((t << 5) + vb * 4) ^ em)]) = h;
  }
}

// one t, one wh: register-chained stage-A -> stage-B (R3..R21-verified mapping)
static __device__ __forceinline__ void compute_wh(
    const bf16x8* xf, const Frags& F, int wh, f32x4& acc0, f32x4& acc1) {
  acc0 = f32x4{0.f, 0.f, 0.f, 0.f};
  acc1 = f32x4{0.f, 0.f, 0.f, 0.f};
  #pragma unroll
  for (int k = 0; k < 3; ++k) {
    #pragma unroll
    for (int ch = 0; ch < 2; ++ch) {
      f32x4 zero = {0.f, 0.f, 0.f, 0.f};
      f32x4 dP = __builtin_amdgcn_mfma_f32_16x16x32_bf16(xf[ch * 2 + 0], F.afrag[k][wh], zero, 0, 0, 0);
      f32x4 dQ = __builtin_amdgcn_mfma_f32_16x16x32_bf16(xf[ch * 2 + 1], F.afrag[k][wh], zero, 0, 0, 0);
      bf16x8 zf;
      zf[0] = tobf(dP[0]); zf[1] = tobf(dP[1]); zf[2] = tobf(dP[2]); zf[3] = tobf(dP[3]);
      zf[4] = tobf(dQ[0]); zf[5] = tobf(dQ[1]); zf[6] = tobf(dQ[2]); zf[7] = tobf(dQ[3]);
      if (ch == 0)
        acc0 = __builtin_amdgcn_mfma_f32_16x16x32_bf16(F.wfrag[k * 2 + ch], zf, acc0, 0, 0, 0);
      else
        acc1 = __builtin_amdgcn_mfma_f32_16x16x32_bf16(F.wfrag[k * 2 + ch], zf, acc1, 0, 0, 0);
    }
  }
}

// ---------------------------------------------------------------------------
// K1: stats-only (NO y store -- no dirty L3, no write-allocate RMW).
// x is L3-warm from k0. Stats accumulate in registers across both tiles.
// ---------------------------------------------------------------------------
__global__ __launch_bounds__(NTHR, 4) void k1_stats(
    const float* __restrict__ x, const float* __restrict__ A,
    const float* __restrict__ W, const float* __restrict__ b,
    float* __restrict__ part) {
  __shared__ __align__(16) SmemU sm;
  __shared__ float stats2[2][2][64];   // [sum|sq][t-half][o]

  const int bid = blockIdx.x;
  const int tid = threadIdx.x;
  const int lane = tid & 63;
  const int wv = tid >> 6;
  const int ob = wv & 3;
  const int th = wv >> 2;
  const int l15 = lane & 15;
  const int lg = lane >> 4;

  stage_wa(A, W, sm, tid);
  __syncthreads();
  Frags F;
  read_frags(sm, b, ob, l15, lg, F);
  __syncthreads();                 // all wa reads done before xs overwrite

  float lsum[4] = {0.f, 0.f, 0.f, 0.f}, lsq[4] = {0.f, 0.f, 0.f, 0.f};

  #pragma unroll
  for (int i = 0; i < 2; ++i) {
    const int tile = bid * 2 + i;
    const int n = tile / NTILE;
    const int t0 = (tile - n * NTILE) * TT;

    stage_x(x, sm, n, t0, tid);
    __syncthreads();

    #pragma unroll 2
    for (int tl = 0; tl < 6; ++tl) {
      const int t = th * 6 + tl;
      bf16x8 xf[4];
      #pragma unroll
      for (int q = 0; q < 4; ++q)
        xf[q] = *reinterpret_cast<const bf16x8*>(sm.xs + F.fK[q] + ((t << 5) ^ F.fS5[q]));
      #pragma unroll
      for (int wh = 0; wh < 2; ++wh) {
        f32x4 acc0, acc1;
        compute_wh(xf, F, wh, acc0, acc1);
        const int w = wh ? 16 + l15 : l15;
        if (w < V_) {
          #pragma unroll
          for (int r = 0; r < 4; ++r) {
            float val = acc0[r] + acc1[r] + F.bs[r];
            lsum[r] += val;
            lsq[r] += val * val;
          }
        }
      }
    }
    __syncthreads();   // all xs reads done before next tile's stage_x
  }

  #pragma unroll
  for (int d = 1; d < 16; d <<= 1) {
    #pragma unroll
    for (int r = 0; r < 4; ++r) {
      lsum[r] += __shfl_xor(lsum[r], d);
      lsq[r]  += __shfl_xor(lsq[r], d);
    }
  }
  if (l15 == 0) {
    #pragma unroll
    for (int r = 0; r < 4; ++r) {
      stats2[0][th][F.obase + r] = lsum[r];
      stats2[1][th][F.obase + r] = lsq[r];
    }
  }
  __syncthreads();
  if (tid < 128)
    part[(size_t)bid * 128 + tid] =
        stats2[tid >> 6][0][tid & 63] + stats2[tid >> 6][1][tid & 63];
}

// ---------------------------------------------------------------------------
// K2: reduce per-block partials -> per-channel scale/shift
// ---------------------------------------------------------------------------
__global__ __launch_bounds__(256) void k2_stats(
    const float* __restrict__ part,
    const float* __restrict__ gamma, const float* __restrict__ beta,
    float* __restrict__ ss) {
  const int o = blockIdx.x;
  const int tid = threadIdx.x;
  double s = 0.0, q = 0.0;
  for (int i = tid; i < NPERS; i += 256) {
    s += (double)part[(size_t)i * 128 + o];
    q += (double)part[(size_t)i * 128 + 64 + o];
  }
  __shared__ double sd[256], qd[256];
  sd[tid] = s; qd[tid] = q;
  __syncthreads();
  for (int step = 128; step > 0; step >>= 1) {
    if (tid < step) { sd[tid] += sd[tid + step]; qd[tid] += qd[tid + step]; }
    __syncthreads();
  }
  if (tid == 0) {
    const double cnt = 480000.0;
    double mean = sd[0] / cnt;
    double var = qd[0] / cnt - mean * mean;
    float inv = rsqrtf((float)var + EPS_);
    float sc = gamma[o] * inv;
    float sh = beta[o] - (float)mean * sc;
    ss[2 * o] = sc;
    ss[2 * o + 1] = sh;
  }
}

// ---------------------------------------------------------------------------
// K3: recompute y (x L3-warm), apply BN + residual (x from LDS, bf16) + relu,
// store out with NON-TEMPORAL stores (out never re-read; keeps L3 clean so
// x stays resident across graph replays -> k0 becomes all-hit).
// ---------------------------------------------------------------------------
__global__ __launch_bounds__(NTHR, 4) void k3_apply(
    const float* __restrict__ x, const float* __restrict__ A,
    const float* __restrict__ W, const float* __restrict__ b,
    const float* __restrict__ ss, float* __restrict__ out) {
  __shared__ __align__(16) SmemU sm;

  const int bid = blockIdx.x;
  const int tid = threadIdx.x;
  const int lane = tid & 63;
  const int wv = tid >> 6;
  const int ob = wv & 3;
  const int th = wv >> 2;
  const int l15 = lane & 15;
  const int lg = lane >> 4;

  stage_wa(A, W, sm, tid);
  __syncthreads();
  Frags F;
  read_frags(sm, b, ob, l15, lg, F);

  float sc[4], sh[4];
  #pragma unroll
  for (int r = 0; r < 4; ++r) {
    sc[r] = ss[2 * (F.obase + r)];
    sh[r] = ss[2 * (F.obase + r) + 1];
  }
  __syncthreads();                 // all wa reads done before xs overwrite

  #pragma unroll
  for (int i = 0; i < 2; ++i) {
    const int tile = bid * 2 + i;
    const int n = tile / NTILE;
    const int t0 = (tile - n * NTILE) * TT;

    stage_x(x, sm, n, t0, tid);
    __syncthreads();

    float* obp = out + (size_t)n * 480000 + (size_t)t0 * 25;

    #pragma unroll 2
    for (int tl = 0; tl < 6; ++tl) {
      const int t = th * 6 + tl;
      bf16x8 xf[4];
      #pragma unroll
      for (int q = 0; q < 4; ++q)
        xf[q] = *reinterpret_cast<const bf16x8*>(sm.xs + F.fK[q] + ((t << 5) ^ F.fS5[q]));
      #pragma unroll
      for (int wh = 0; wh < 2; ++wh) {
        f32x4 acc0, acc1;
        compute_wh(xf, F, wh, acc0, acc1);
        const int w = wh ? 16 + l15 : l15;
        if (w < V_) {
          #pragma unroll
          for (int r = 0; r < 4; ++r) {
            const int o = F.obase + r;
            float val = acc0[r] + acc1[r] + F.bs[r];
            float xr = (float)sm.xs[o * XROW + (((t << 5) + w) ^ emask(o))];
            float res = fmaxf(sc[r] * val + sh[r] + xr, 0.f);
            __builtin_nontemporal_store(res, &obp[(size_t)o * 7500 + t * 25 + w]);
          }
        }
      }
    }
    __syncthreads();   // all xs reads done before next tile's stage_x
  }
}

extern "C" void kernel_launch(void* const* d_in, const int* in_sizes, int n_in,
                              void* d_out, int out_size, void* d_ws, size_t ws_size,
                              hipStream_t stream) {
  const float* x     = (const float*)d_in[0];
  const float* A     = (const float*)d_in[1];
  const float* W     = (const float*)d_in[2];
  const float* b     = (const float*)d_in[3];
  const float* gamma = (const float*)d_in[4];
  const float* beta  = (const float*)d_in[5];
  float* out = (float*)d_out;

  float* part = (float*)d_ws;                // NPERS*128 floats
  float* ss   = part + (size_t)NPERS * 128;  // 128 floats

  k0_warm<<<2048, 256, 0, stream>>>(x);
  k1_stats<<<NPERS, NTHR, 0, stream>>>(x, A, W, b, part);
  k2_stats<<<64, 256, 0, stream>>>(part, gamma, beta, ss);
  k3_apply<<<NPERS, NTHR, 0, stream>>>(x, A, W, b, ss, out);
}

// Round 23
// 163.376 us; speedup vs baseline: 1.5834x; 1.5834x over previous
//
#include <hip/hip_runtime.h>
#include <hip/hip_bf16.h>

// Problem constants
#define N_ 64
#define C_ 64
#define T_ 300
#define V_ 25
#define K_ 3
#define TT 12             // t-values per tile
#define NTILE 25          // T_/TT
#define NBLK 1600         // total tiles
#define NPERS 768         // = 3 blocks/CU x 256 CU: ALL blocks co-resident.
                          // R18's 800 blocks ran as 2 full generations (123us);
                          // 768 + 2/3-tile split = single generation + 1-tile tail.
#define XROW 384          // xs row pitch in elems: TT*32
#define WP 72             // W-lds row pitch (144B, 16B-aligned b128 frag reads)
#define ATP 40            // At-lds row pitch (80B, 16B-aligned b128 frag reads)
#define NTHR 512          // 8 waves: (ob 0..3) x (t-half 0..1)
#define EPS_ 1e-5f

typedef __bf16 bf16_t;
typedef __bf16 bf16x4 __attribute__((ext_vector_type(4)));
typedef __bf16 bf16x8 __attribute__((ext_vector_type(8)));
typedef float f32x4 __attribute__((ext_vector_type(4)));
typedef float f32x4u __attribute__((ext_vector_type(4), aligned(4)));

static __device__ __forceinline__ bf16_t tobf(float f) { return (bf16_t)f; }
// element-index swizzle within a c-row (XOR of bits 3..5: keeps 4-runs contiguous)
static __device__ __forceinline__ int emask(int c) { return ((c & 3) << 3) | ((c & 8) << 2); }

// LDS overlay: W/A staging (prologue only; frags move to registers) reuses xs.
union SmemU {
  struct { bf16_t W[3 * 64 * WP]; bf16_t At[3 * 32 * ATP]; } wa;   // 35.3KB
  bf16_t xs[64 * XROW];                                            // 48KB
};

struct Frags {
  bf16x8 wfrag[6];
  bf16x8 afrag[3][2];
  int fK[4], fS5[4];
  float bs[4];
  int obase;
};

// ---- coalesced W/A global->LDS staging (bf16)
static __device__ __forceinline__ void stage_wa(
    const float* __restrict__ A, const float* __restrict__ W, SmemU& sm, int tid) {
  for (int m = tid; m < 3072; m += NTHR) {
    f32x4 v4 = *(reinterpret_cast<const f32x4*>(W) + m);
    int f = m << 2;
    int k = f >> 12, o = (f >> 6) & 63, c = f & 63;
    bf16x4 h;
    h[0] = tobf(v4[0]); h[1] = tobf(v4[1]); h[2] = tobf(v4[2]); h[3] = tobf(v4[3]);
    *reinterpret_cast<bf16x4*>(&sm.wa.W[(k * 64 + o) * WP + c]) = h;
  }
  for (int i = tid; i < 3072; i += NTHR) {
    int k = i >> 10, r = i & 1023, w = r >> 5, v = r & 31;
    float val = (v < V_ && w < V_) ? A[k * 625 + v * 25 + w] : 0.f;
    sm.wa.At[(k * 32 + w) * ATP + v] = tobf(val);
  }
}

static __device__ __forceinline__ void read_frags(
    const SmemU& sm, const float* __restrict__ b, int ob, int l15, int lg, Frags& F) {
  const int o = ob * 16 + l15;
  #pragma unroll
  for (int k = 0; k < 3; ++k)
    #pragma unroll
    for (int ch = 0; ch < 2; ++ch)
      F.wfrag[k * 2 + ch] =
          *reinterpret_cast<const bf16x8*>(&sm.wa.W[(k * 64 + o) * WP + ch * 32 + lg * 8]);
  #pragma unroll
  for (int k = 0; k < 3; ++k)
    #pragma unroll
    for (int wh = 0; wh < 2; ++wh)
      F.afrag[k][wh] =
          *reinterpret_cast<const bf16x8*>(&sm.wa.At[(k * 32 + wh * 16 + l15) * ATP + lg * 8]);
  // per-lane fragment LDS offsets. Permuted c-map (R3..R22-verified):
  // frag q=(chalf,sub): c = chalf*32 + sub*4 + 8*(l15>>2) + (l15&3)
  const int crow = 8 * (l15 >> 2) + (l15 & 3);
  #pragma unroll
  for (int q = 0; q < 4; ++q) {
    int c = ((q >> 1) * 32) + ((q & 1) * 4) + crow;
    int em = emask(c);
    F.fK[q] = c * XROW + ((lg * 8) ^ (em & 24));
    F.fS5[q] = em & 32;
  }
  F.obase = ob * 16 + lg * 4;
  #pragma unroll
  for (int r = 0; r < 4; ++r)
    F.bs[r] = b[F.obase + r] + b[64 + F.obase + r] + b[128 + F.obase + r];
}

// ---- overlapped touch: issue 3 line-strided loads of a FUTURE tile's x.
// Consumption (sink add) MUST sit after covering compute -- consuming before
// a barrier forces a vmcnt drain and serializes the HBM pull (R14/R16 bug).
static __device__ __forceinline__ void touch_issue(
    const float* __restrict__ x, int tile, int tid, float* tv) {
  const int n = tile / NTILE;
  const int t0 = (tile - n * NTILE) * TT;
  const float* base = x + (size_t)n * 480000 + (size_t)t0 * 25;
  #pragma unroll
  for (int j = 0; j < 3; ++j) {
    int idx = tid + (j << 9);          // 0..1535
    int c = idx / 19;                  // 19 lines (64B) per c-row
    int li = idx - c * 19;
    tv[j] = (c < 64) ? base[(size_t)c * 7500 + li * 16] : 0.f;
  }
}

// ---- x staging: 512 threads = 64 c-rows x 8 v-blocks; pure bit-op indexing.
static __device__ __forceinline__ void stage_x(
    const float* __restrict__ x, SmemU& sm, int n, int t0, int tid) {
  const int c = tid >> 3, vb = tid & 7;
  const int em = emask(c);
  const float* xr = x + (size_t)n * 480000 + (size_t)c * 7500 + (size_t)t0 * 25;
  bf16_t* xsr = &sm.xs[c * XROW];
  #pragma unroll
  for (int t = 0; t < TT; ++t) {
    bf16x4 h;
    if (vb < 6) {
      f32x4u v4 = *reinterpret_cast<const f32x4u*>(xr + t * 25 + vb * 4);
      h[0] = tobf(v4[0]); h[1] = tobf(v4[1]); h[2] = tobf(v4[2]); h[3] = tobf(v4[3]);
    } else if (vb == 6) {
      float s = xr[t * 25 + 24];
      h[0] = tobf(s); h[1] = tobf(0.f); h[2] = tobf(0.f); h[3] = tobf(0.f);
    } else {
      h[0] = tobf(0.f); h[1] = tobf(0.f); h[2] = tobf(0.f); h[3] = tobf(0.f);
    }
    *reinterpret_cast<bf16x4*>(&xsr[(((t << 5) + vb * 4) ^ em)]) = h;
  }
}

// one t, one wh: register-chained stage-A -> stage-B (R3..R22-verified mapping)
static __device__ __forceinline__ void compute_wh(
    const bf16x8* xf, const Frags& F, int wh, f32x4& acc0, f32x4& acc1) {
  acc0 = f32x4{0.f, 0.f, 0.f, 0.f};
  acc1 = f32x4{0.f, 0.f, 0.f, 0.f};
  #pragma unroll
  for (int k = 0; k < 3; ++k) {
    #pragma unroll
    for (int ch = 0; ch < 2; ++ch) {
      f32x4 zero = {0.f, 0.f, 0.f, 0.f};
      f32x4 dP = __builtin_amdgcn_mfma_f32_16x16x32_bf16(xf[ch * 2 + 0], F.afrag[k][wh], zero, 0, 0, 0);
      f32x4 dQ = __builtin_amdgcn_mfma_f32_16x16x32_bf16(xf[ch * 2 + 1], F.afrag[k][wh], zero, 0, 0, 0);
      bf16x8 zf;
      zf[0] = tobf(dP[0]); zf[1] = tobf(dP[1]); zf[2] = tobf(dP[2]); zf[3] = tobf(dP[3]);
      zf[4] = tobf(dQ[0]); zf[5] = tobf(dQ[1]); zf[6] = tobf(dQ[2]); zf[7] = tobf(dQ[3]);
      if (ch == 0)
        acc0 = __builtin_amdgcn_mfma_f32_16x16x32_bf16(F.wfrag[k * 2 + ch], zf, acc0, 0, 0, 0);
      else
        acc1 = __builtin_amdgcn_mfma_f32_16x16x32_bf16(F.wfrag[k * 2 + ch], zf, acc1, 0, 0, 0);
    }
  }
}

// ---------------------------------------------------------------------------
// K1: compute y (stored to d_out staging) + per-block channel partials.
// Grid = 768 (all co-resident, ONE generation). Blocks 0..63 own 3 tiles
// (start 3*bid), blocks 64..767 own 2 (start 192+2*(bid-64)). Touch warms
// the next tile under the current tile's compute (R15-validated).
// ---------------------------------------------------------------------------
__global__ __launch_bounds__(NTHR, 4) void k1_compute(
    const float* __restrict__ x, const float* __restrict__ A,
    const float* __restrict__ W, const float* __restrict__ b,
    float* __restrict__ y, float* __restrict__ part) {
  __shared__ __align__(16) SmemU sm;
  __shared__ float stats2[2][2][64];   // [sum|sq][t-half][o]

  const int bid = blockIdx.x;
  const int tid = threadIdx.x;
  const int lane = tid & 63;
  const int wv = tid >> 6;
  const int ob = wv & 3;
  const int th = wv >> 2;
  const int l15 = lane & 15;
  const int lg = lane >> 4;

  const int nt = (bid < 64) ? 3 : 2;
  const int start = (bid < 64) ? bid * 3 : 192 + (bid - 64) * 2;

  stage_wa(A, W, sm, tid);
  __syncthreads();
  Frags F;
  read_frags(sm, b, ob, l15, lg, F);
  __syncthreads();                 // all wa reads done before xs overwrite

  float lsum[4] = {0.f, 0.f, 0.f, 0.f}, lsq[4] = {0.f, 0.f, 0.f, 0.f};
  float sink = 0.f;

  for (int i = 0; i < nt; ++i) {
    const int tile = start + i;
    const int n = tile / NTILE;
    const int t0 = (tile - n * NTILE) * TT;

    stage_x(x, sm, n, t0, tid);
    __syncthreads();

    float tv[3] = {0.f, 0.f, 0.f};
    if (i + 1 < nt) touch_issue(x, tile + 1, tid, tv);  // warm next tile

    float* yb = y + (size_t)n * 480000 + (size_t)t0 * 25;

    #pragma unroll 2
    for (int tl = 0; tl < 6; ++tl) {
      const int t = th * 6 + tl;
      bf16x8 xf[4];
      #pragma unroll
      for (int q = 0; q < 4; ++q)
        xf[q] = *reinterpret_cast<const bf16x8*>(sm.xs + F.fK[q] + ((t << 5) ^ F.fS5[q]));
      #pragma unroll
      for (int wh = 0; wh < 2; ++wh) {
        f32x4 acc0, acc1;
        compute_wh(xf, F, wh, acc0, acc1);
        const int w = wh ? 16 + l15 : l15;
        if (w < V_) {
          #pragma unroll
          for (int r = 0; r < 4; ++r) {
            float val = acc0[r] + acc1[r] + F.bs[r];
            lsum[r] += val;
            lsq[r] += val * val;
            yb[(size_t)(F.obase + r) * 7500 + t * 25 + w] = val;
          }
        }
      }
    }
    sink += tv[0] + tv[1] + tv[2];   // touch consumption AFTER compute
    __syncthreads();   // all xs reads done before next tile's stage_x
  }
  asm volatile("" :: "v"(sink));     // keep touches alive (rule #17)

  #pragma unroll
  for (int d = 1; d < 16; d <<= 1) {
    #pragma unroll
    for (int r = 0; r < 4; ++r) {
      lsum[r] += __shfl_xor(lsum[r], d);
      lsq[r]  += __shfl_xor(lsq[r], d);
    }
  }
  if (l15 == 0) {
    #pragma unroll
    for (int r = 0; r < 4; ++r) {
      stats2[0][th][F.obase + r] = lsum[r];
      stats2[1][th][F.obase + r] = lsq[r];
    }
  }
  __syncthreads();
  if (tid < 128)
    part[(size_t)bid * 128 + tid] =
        stats2[tid >> 6][0][tid & 63] + stats2[tid >> 6][1][tid & 63];
}

// ---------------------------------------------------------------------------
// K2: reduce per-block partials -> per-channel scale/shift
// ---------------------------------------------------------------------------
__global__ __launch_bounds__(256) void k2_stats(
    const float* __restrict__ part,
    const float* __restrict__ gamma, const float* __restrict__ beta,
    float* __restrict__ ss) {
  const int o = blockIdx.x;
  const int tid = threadIdx.x;
  double s = 0.0, q = 0.0;
  for (int i = tid; i < NPERS; i += 256) {
    s += (double)part[(size_t)i * 128 + o];
    q += (double)part[(size_t)i * 128 + 64 + o];
  }
  __shared__ double sd[256], qd[256];
  sd[tid] = s; qd[tid] = q;
  __syncthreads();
  for (int step = 128; step > 0; step >>= 1) {
    if (tid < step) { sd[tid] += sd[tid + step]; qd[tid] += qd[tid + step]; }
    __syncthreads();
  }
  if (tid == 0) {
    const double cnt = 480000.0;
    double mean = sd[0] / cnt;
    double var = qd[0] / cnt - mean * mean;
    float inv = rsqrtf((float)var + EPS_);
    float sc = gamma[o] * inv;
    float sh = beta[o] - (float)mean * sc;
    ss[2 * o] = sc;
    ss[2 * o + 1] = sh;
  }
}

// ---------------------------------------------------------------------------
// K3: out = relu(scale[c]*y + shift[c] + x), in place on d_out (y staged
// there). VECTOR (16B) non-temporal stores only -- R22 showed scalar 4B nt
// stores bypass cache coalescing and double write traffic.
// ---------------------------------------------------------------------------
__global__ __launch_bounds__(256) void k3_finish(
    const float* __restrict__ x, const float* __restrict__ ss,
    float* __restrict__ y) {
  const int p = blockIdx.x;       // 0..4095 = n*64 + c
  const int c = p & 63;
  const float sc = ss[2 * c];
  const float sh = ss[2 * c + 1];
  const f32x4* xv = reinterpret_cast<const f32x4*>(x + (size_t)p * 7500);
  f32x4* yv = reinterpret_cast<f32x4*>(y + (size_t)p * 7500);
  for (int i = threadIdx.x; i < 1875; i += 256) {
    f32x4 a = yv[i];
    f32x4 b4 = xv[i];
    f32x4 o;
    o[0] = fmaxf(sc * a[0] + sh + b4[0], 0.f);
    o[1] = fmaxf(sc * a[1] + sh + b4[1], 0.f);
    o[2] = fmaxf(sc * a[2] + sh + b4[2], 0.f);
    o[3] = fmaxf(sc * a[3] + sh + b4[3], 0.f);
    __builtin_nontemporal_store(o, yv + i);
  }
}

extern "C" void kernel_launch(void* const* d_in, const int* in_sizes, int n_in,
                              void* d_out, int out_size, void* d_ws, size_t ws_size,
                              hipStream_t stream) {
  const float* x     = (const float*)d_in[0];
  const float* A     = (const float*)d_in[1];
  const float* W     = (const float*)d_in[2];
  const float* b     = (const float*)d_in[3];
  const float* gamma = (const float*)d_in[4];
  const float* beta  = (const float*)d_in[5];
  float* y = (float*)d_out;                  // stage y in d_out, finish in place

  float* part = (float*)d_ws;                // NPERS*128 floats
  float* ss   = part + (size_t)NPERS * 128;  // 128 floats

  k1_compute<<<NPERS, NTHR, 0, stream>>>(x, A, W, b, y, part);
  k2_stats<<<64, 256, 0, stream>>>(part, gamma, beta, ss);
  k3_finish<<<4096, 256, 0, stream>>>(x, ss, y);
}

// Round 24
// 142.485 us; speedup vs baseline: 1.8156x; 1.1466x over previous
//
#include <hip/hip_runtime.h>
#include <hip/hip_bf16.h>

// Problem constants
#define N_ 64
#define C_ 64
#define T_ 300
#define V_ 25
#define K_ 3
#define TT 12             // t-values per tile
#define NTILE 25          // T_/TT
#define NBLK 1600         // total tiles
#define NPERS 800         // blocks; block bid owns tiles 2*bid, 2*bid+1
#define XROW 384          // xs row pitch in elems: TT*32
#define WP 72             // W-lds row pitch (144B, 16B-aligned b128 frag reads)
#define ATP 40            // At-lds row pitch (80B, 16B-aligned b128 frag reads)
#define NTHR 512          // 8 waves: (ob 0..3) x (t-half 0..1)
#define EPS_ 1e-5f

typedef __bf16 bf16_t;
typedef __bf16 bf16x4 __attribute__((ext_vector_type(4)));
typedef __bf16 bf16x8 __attribute__((ext_vector_type(8)));
typedef float f32x4 __attribute__((ext_vector_type(4)));
typedef float f32x4u __attribute__((ext_vector_type(4), aligned(4)));

static __device__ __forceinline__ bf16_t tobf(float f) { return (bf16_t)f; }
// element-index swizzle within a c-row (XOR of bits 3..5: keeps 4-runs contiguous)
static __device__ __forceinline__ int emask(int c) { return ((c & 3) << 3) | ((c & 8) << 2); }

// LDS overlay: W/A staging (prologue only; frags move to registers) reuses xs.
union SmemU {
  struct { bf16_t W[3 * 64 * WP]; bf16_t At[3 * 32 * ATP]; } wa;   // 35.3KB
  bf16_t xs[64 * XROW];                                            // 48KB
};

struct Frags {
  bf16x8 wfrag[6];
  bf16x8 afrag[3][2];
  int fK[4], fS5[4];
  float bs[4];
  int obase;
};

// ---- coalesced W/A global->LDS staging (bf16)
static __device__ __forceinline__ void stage_wa(
    const float* __restrict__ A, const float* __restrict__ W, SmemU& sm, int tid) {
  for (int m = tid; m < 3072; m += NTHR) {
    f32x4 v4 = *(reinterpret_cast<const f32x4*>(W) + m);
    int f = m << 2;
    int k = f >> 12, o = (f >> 6) & 63, c = f & 63;
    bf16x4 h;
    h[0] = tobf(v4[0]); h[1] = tobf(v4[1]); h[2] = tobf(v4[2]); h[3] = tobf(v4[3]);
    *reinterpret_cast<bf16x4*>(&sm.wa.W[(k * 64 + o) * WP + c]) = h;
  }
  for (int i = tid; i < 3072; i += NTHR) {
    int k = i >> 10, r = i & 1023, w = r >> 5, v = r & 31;
    float val = (v < V_ && w < V_) ? A[k * 625 + v * 25 + w] : 0.f;
    sm.wa.At[(k * 32 + w) * ATP + v] = tobf(val);
  }
}

static __device__ __forceinline__ void read_frags(
    const SmemU& sm, const float* __restrict__ b, int ob, int l15, int lg, Frags& F) {
  const int o = ob * 16 + l15;
  #pragma unroll
  for (int k = 0; k < 3; ++k)
    #pragma unroll
    for (int ch = 0; ch < 2; ++ch)
      F.wfrag[k * 2 + ch] =
          *reinterpret_cast<const bf16x8*>(&sm.wa.W[(k * 64 + o) * WP + ch * 32 + lg * 8]);
  #pragma unroll
  for (int k = 0; k < 3; ++k)
    #pragma unroll
    for (int wh = 0; wh < 2; ++wh)
      F.afrag[k][wh] =
          *reinterpret_cast<const bf16x8*>(&sm.wa.At[(k * 32 + wh * 16 + l15) * ATP + lg * 8]);
  // per-lane fragment LDS offsets. Permuted c-map (R3..R23-verified):
  // frag q=(chalf,sub): c = chalf*32 + sub*4 + 8*(l15>>2) + (l15&3)
  const int crow = 8 * (l15 >> 2) + (l15 & 3);
  #pragma unroll
  for (int q = 0; q < 4; ++q) {
    int c = ((q >> 1) * 32) + ((q & 1) * 4) + crow;
    int em = emask(c);
    F.fK[q] = c * XROW + ((lg * 8) ^ (em & 24));
    F.fS5[q] = em & 32;
  }
  F.obase = ob * 16 + lg * 4;
  #pragma unroll
  for (int r = 0; r < 4; ++r)
    F.bs[r] = b[F.obase + r] + b[64 + F.obase + r] + b[128 + F.obase + r];
}

// ---- overlapped touch: issue 3 line-strided loads of a FUTURE tile's x.
// Consumption (sink add) MUST sit after covering compute -- consuming before
// a barrier forces a vmcnt drain and serializes the HBM pull (R14/R16 bug).
static __device__ __forceinline__ void touch_issue(
    const float* __restrict__ x, int tile, int tid, float* tv) {
  const int n = tile / NTILE;
  const int t0 = (tile - n * NTILE) * TT;
  const float* base = x + (size_t)n * 480000 + (size_t)t0 * 25;
  #pragma unroll
  for (int j = 0; j < 3; ++j) {
    int idx = tid + (j << 9);          // 0..1535
    int c = idx / 19;                  // 19 lines (64B) per c-row
    int li = idx - c * 19;
    tv[j] = (c < 64) ? base[(size_t)c * 7500 + li * 16] : 0.f;
  }
}

// ---- x staging: 512 threads = 64 c-rows x 8 v-blocks; pure bit-op indexing.
static __device__ __forceinline__ void stage_x(
    const float* __restrict__ x, SmemU& sm, int n, int t0, int tid) {
  const int c = tid >> 3, vb = tid & 7;
  const int em = emask(c);
  const float* xr = x + (size_t)n * 480000 + (size_t)c * 7500 + (size_t)t0 * 25;
  bf16_t* xsr = &sm.xs[c * XROW];
  #pragma unroll
  for (int t = 0; t < TT; ++t) {
    bf16x4 h;
    if (vb < 6) {
      f32x4u v4 = *reinterpret_cast<const f32x4u*>(xr + t * 25 + vb * 4);
      h[0] = tobf(v4[0]); h[1] = tobf(v4[1]); h[2] = tobf(v4[2]); h[3] = tobf(v4[3]);
    } else if (vb == 6) {
      float s = xr[t * 25 + 24];
      h[0] = tobf(s); h[1] = tobf(0.f); h[2] = tobf(0.f); h[3] = tobf(0.f);
    } else {
      h[0] = tobf(0.f); h[1] = tobf(0.f); h[2] = tobf(0.f); h[3] = tobf(0.f);
    }
    *reinterpret_cast<bf16x4*>(&xsr[(((t << 5) + vb * 4) ^ em)]) = h;
  }
}

// one t, one wh: register-chained stage-A -> stage-B (R3..R23-verified mapping)
static __device__ __forceinline__ void compute_wh(
    const bf16x8* xf, const Frags& F, int wh, f32x4& acc0, f32x4& acc1) {
  acc0 = f32x4{0.f, 0.f, 0.f, 0.f};
  acc1 = f32x4{0.f, 0.f, 0.f, 0.f};
  #pragma unroll
  for (int k = 0; k < 3; ++k) {
    #pragma unroll
    for (int ch = 0; ch < 2; ++ch) {
      f32x4 zero = {0.f, 0.f, 0.f, 0.f};
      f32x4 dP = __builtin_amdgcn_mfma_f32_16x16x32_bf16(xf[ch * 2 + 0], F.afrag[k][wh], zero, 0, 0, 0);
      f32x4 dQ = __builtin_amdgcn_mfma_f32_16x16x32_bf16(xf[ch * 2 + 1], F.afrag[k][wh], zero, 0, 0, 0);
      bf16x8 zf;
      zf[0] = tobf(dP[0]); zf[1] = tobf(dP[1]); zf[2] = tobf(dP[2]); zf[3] = tobf(dP[3]);
      zf[4] = tobf(dQ[0]); zf[5] = tobf(dQ[1]); zf[6] = tobf(dQ[2]); zf[7] = tobf(dQ[3]);
      if (ch == 0)
        acc0 = __builtin_amdgcn_mfma_f32_16x16x32_bf16(F.wfrag[k * 2 + ch], zf, acc0, 0, 0, 0);
      else
        acc1 = __builtin_amdgcn_mfma_f32_16x16x32_bf16(F.wfrag[k * 2 + ch], zf, acc1, 0, 0, 0);
    }
  }
}

// ---------------------------------------------------------------------------
// K1: compute y (stored to d_out staging) + per-block channel partials.
// Tile 1's cache lines pulled by overlapped touches under tile-0's compute.
// (R18 configuration -- measured best: k1 123us, total 141.4us.)
// ---------------------------------------------------------------------------
__global__ __launch_bounds__(NTHR, 4) void k1_compute(
    const float* __restrict__ x, const float* __restrict__ A,
    const float* __restrict__ W, const float* __restrict__ b,
    float* __restrict__ y, float* __restrict__ part) {
  __shared__ __align__(16) SmemU sm;
  __shared__ float stats2[2][2][64];   // [sum|sq][t-half][o]

  const int bid = blockIdx.x;
  const int tid = threadIdx.x;
  const int lane = tid & 63;
  const int wv = tid >> 6;
  const int ob = wv & 3;
  const int th = wv >> 2;
  const int l15 = lane & 15;
  const int lg = lane >> 4;

  stage_wa(A, W, sm, tid);
  __syncthreads();
  Frags F;
  read_frags(sm, b, ob, l15, lg, F);
  __syncthreads();                 // all wa reads done before xs overwrite

  float lsum[4] = {0.f, 0.f, 0.f, 0.f}, lsq[4] = {0.f, 0.f, 0.f, 0.f};
  float sink = 0.f;

  #pragma unroll
  for (int i = 0; i < 2; ++i) {
    const int tile = bid * 2 + i;
    const int n = tile / NTILE;
    const int t0 = (tile - n * NTILE) * TT;

    stage_x(x, sm, n, t0, tid);
    __syncthreads();

    float tv[3] = {0.f, 0.f, 0.f};
    if (i == 0) touch_issue(x, tile + 1, tid, tv);   // warm tile 1 under compute

    float* yb = y + (size_t)n * 480000 + (size_t)t0 * 25;

    #pragma unroll 2
    for (int tl = 0; tl < 6; ++tl) {
      const int t = th * 6 + tl;
      bf16x8 xf[4];
      #pragma unroll
      for (int q = 0; q < 4; ++q)
        xf[q] = *reinterpret_cast<const bf16x8*>(sm.xs + F.fK[q] + ((t << 5) ^ F.fS5[q]));
      #pragma unroll
      for (int wh = 0; wh < 2; ++wh) {
        f32x4 acc0, acc1;
        compute_wh(xf, F, wh, acc0, acc1);
        const int w = wh ? 16 + l15 : l15;
        if (w < V_) {
          #pragma unroll
          for (int r = 0; r < 4; ++r) {
            float val = acc0[r] + acc1[r] + F.bs[r];
            lsum[r] += val;
            lsq[r] += val * val;
            yb[(size_t)(F.obase + r) * 7500 + t * 25 + w] = val;
          }
        }
      }
    }
    sink += tv[0] + tv[1] + tv[2];   // touch consumption AFTER compute
    __syncthreads();   // all xs reads done before next tile's stage_x
  }
  asm volatile("" :: "v"(sink));     // keep touches alive (rule #17)

  #pragma unroll
  for (int d = 1; d < 16; d <<= 1) {
    #pragma unroll
    for (int r = 0; r < 4; ++r) {
      lsum[r] += __shfl_xor(lsum[r], d);
      lsq[r]  += __shfl_xor(lsq[r], d);
    }
  }
  if (l15 == 0) {
    #pragma unroll
    for (int r = 0; r < 4; ++r) {
      stats2[0][th][F.obase + r] = lsum[r];
      stats2[1][th][F.obase + r] = lsq[r];
    }
  }
  __syncthreads();
  if (tid < 128)
    part[(size_t)bid * 128 + tid] =
        stats2[tid >> 6][0][tid & 63] + stats2[tid >> 6][1][tid & 63];
}

// ---------------------------------------------------------------------------
// K2: reduce per-block partials -> per-channel scale/shift
// ---------------------------------------------------------------------------
__global__ __launch_bounds__(256) void k2_stats(
    const float* __restrict__ part,
    const float* __restrict__ gamma, const float* __restrict__ beta,
    float* __restrict__ ss) {
  const int o = blockIdx.x;
  const int tid = threadIdx.x;
  double s = 0.0, q = 0.0;
  for (int i = tid; i < NPERS; i += 256) {
    s += (double)part[(size_t)i * 128 + o];
    q += (double)part[(size_t)i * 128 + 64 + o];
  }
  __shared__ double sd[256], qd[256];
  sd[tid] = s; qd[tid] = q;
  __syncthreads();
  for (int step = 128; step > 0; step >>= 1) {
    if (tid < step) { sd[tid] += sd[tid + step]; qd[tid] += qd[tid + step]; }
    __syncthreads();
  }
  if (tid == 0) {
    const double cnt = 480000.0;
    double mean = sd[0] / cnt;
    double var = qd[0] / cnt - mean * mean;
    float inv = rsqrtf((float)var + EPS_);
    float sc = gamma[o] * inv;
    float sh = beta[o] - (float)mean * sc;
    ss[2 * o] = sc;
    ss[2 * o + 1] = sh;
  }
}

// ---------------------------------------------------------------------------
// K3: out = relu(scale[c]*y + shift[c] + x), in place on d_out (y staged
// there). VECTOR (16B) non-temporal stores (scalar nt stores double write
// traffic -- R22).
// ---------------------------------------------------------------------------
__global__ __launch_bounds__(256) void k3_finish(
    const float* __restrict__ x, const float* __restrict__ ss,
    float* __restrict__ y) {
  const int p = blockIdx.x;       // 0..4095 = n*64 + c
  const int c = p & 63;
  const float sc = ss[2 * c];
  const float sh = ss[2 * c + 1];
  const f32x4* xv = reinterpret_cast<const f32x4*>(x + (size_t)p * 7500);
  f32x4* yv = reinterpret_cast<f32x4*>(y + (size_t)p * 7500);
  for (int i = threadIdx.x; i < 1875; i += 256) {
    f32x4 a = yv[i];
    f32x4 b4 = xv[i];
    f32x4 o;
    o[0] = fmaxf(sc * a[0] + sh + b4[0], 0.f);
    o[1] = fmaxf(sc * a[1] + sh + b4[1], 0.f);
    o[2] = fmaxf(sc * a[2] + sh + b4[2], 0.f);
    o[3] = fmaxf(sc * a[3] + sh + b4[3], 0.f);
    __builtin_nontemporal_store(o, yv + i);
  }
}

extern "C" void kernel_launch(void* const* d_in, const int* in_sizes, int n_in,
                              void* d_out, int out_size, void* d_ws, size_t ws_size,
                              hipStream_t stream) {
  const float* x     = (const float*)d_in[0];
  const float* A     = (const float*)d_in[1];
  const float* W     = (const float*)d_in[2];
  const float* b     = (const float*)d_in[3];
  const float* gamma = (const float*)d_in[4];
  const float* beta  = (const float*)d_in[5];
  float* y = (float*)d_out;                  // stage y in d_out, finish in place

  float* part = (float*)d_ws;                // NPERS*128 floats
  float* ss   = part + (size_t)NPERS * 128;  // 128 floats

  k1_compute<<<NPERS, NTHR, 0, stream>>>(x, A, W, b, y, part);
  k2_stats<<<64, 256, 0, stream>>>(part, gamma, beta, ss);
  k3_finish<<<4096, 256, 0, stream>>>(x, ss, y);
}

// Round 25
// 142.333 us; speedup vs baseline: 1.8175x; 1.0011x over previous
//
#include <hip/hip_runtime.h>
#include <hip/hip_bf16.h>

// Problem constants
#define N_ 64
#define C_ 64
#define T_ 300
#define V_ 25
#define K_ 3
#define TT 12             // t-values per tile
#define NTILE 25          // T_/TT
#define NBLK 1600         // total tiles
#define NPERS 800         // blocks; block bid owns tiles 2*bid, 2*bid+1
#define XROW 384          // xs row pitch in elems: TT*32
#define WP 72             // W-lds row pitch (144B, 16B-aligned b128 frag reads)
#define ATP 40            // At-lds row pitch (80B, 16B-aligned b128 frag reads)
#define NTHR 512          // 8 waves: (ob 0..3) x (t-half 0..1)
#define EPS_ 1e-5f
// ystage: per (t, ob) chunk of 512 bf16 = [wh][r][lane] -> 128B fully-covered
// stores per instruction. Total 64*300*4*512 bf16 = 78.6MB.
#define YELEMS ((size_t)64 * 300 * 4 * 512)

typedef __bf16 bf16_t;
typedef __bf16 bf16x4 __attribute__((ext_vector_type(4)));
typedef __bf16 bf16x8 __attribute__((ext_vector_type(8)));
typedef float f32x4 __attribute__((ext_vector_type(4)));
typedef float f32x4u __attribute__((ext_vector_type(4), aligned(4)));

static __device__ __forceinline__ bf16_t tobf(float f) { return (bf16_t)f; }
// element-index swizzle within a c-row (XOR of bits 3..5: keeps 4-runs contiguous)
static __device__ __forceinline__ int emask(int c) { return ((c & 3) << 3) | ((c & 8) << 2); }

// LDS overlay: W/A staging (prologue only; frags move to registers) reuses xs.
union SmemU {
  struct { bf16_t W[3 * 64 * WP]; bf16_t At[3 * 32 * ATP]; } wa;   // 35.3KB
  bf16_t xs[64 * XROW];                                            // 48KB
};

struct Frags {
  bf16x8 wfrag[6];
  bf16x8 afrag[3][2];
  int fK[4], fS5[4];
  float bs[4];
  int obase;
};

// ---- coalesced W/A global->LDS staging (bf16)
static __device__ __forceinline__ void stage_wa(
    const float* __restrict__ A, const float* __restrict__ W, SmemU& sm, int tid) {
  for (int m = tid; m < 3072; m += NTHR) {
    f32x4 v4 = *(reinterpret_cast<const f32x4*>(W) + m);
    int f = m << 2;
    int k = f >> 12, o = (f >> 6) & 63, c = f & 63;
    bf16x4 h;
    h[0] = tobf(v4[0]); h[1] = tobf(v4[1]); h[2] = tobf(v4[2]); h[3] = tobf(v4[3]);
    *reinterpret_cast<bf16x4*>(&sm.wa.W[(k * 64 + o) * WP + c]) = h;
  }
  for (int i = tid; i < 3072; i += NTHR) {
    int k = i >> 10, r = i & 1023, w = r >> 5, v = r & 31;
    float val = (v < V_ && w < V_) ? A[k * 625 + v * 25 + w] : 0.f;
    sm.wa.At[(k * 32 + w) * ATP + v] = tobf(val);
  }
}

static __device__ __forceinline__ void read_frags(
    const SmemU& sm, const float* __restrict__ b, int ob, int l15, int lg, Frags& F) {
  const int o = ob * 16 + l15;
  #pragma unroll
  for (int k = 0; k < 3; ++k)
    #pragma unroll
    for (int ch = 0; ch < 2; ++ch)
      F.wfrag[k * 2 + ch] =
          *reinterpret_cast<const bf16x8*>(&sm.wa.W[(k * 64 + o) * WP + ch * 32 + lg * 8]);
  #pragma unroll
  for (int k = 0; k < 3; ++k)
    #pragma unroll
    for (int wh = 0; wh < 2; ++wh)
      F.afrag[k][wh] =
          *reinterpret_cast<const bf16x8*>(&sm.wa.At[(k * 32 + wh * 16 + l15) * ATP + lg * 8]);
  // per-lane fragment LDS offsets. Permuted c-map (R3..R24-verified):
  // frag q=(chalf,sub): c = chalf*32 + sub*4 + 8*(l15>>2) + (l15&3)
  const int crow = 8 * (l15 >> 2) + (l15 & 3);
  #pragma unroll
  for (int q = 0; q < 4; ++q) {
    int c = ((q >> 1) * 32) + ((q & 1) * 4) + crow;
    int em = emask(c);
    F.fK[q] = c * XROW + ((lg * 8) ^ (em & 24));
    F.fS5[q] = em & 32;
  }
  F.obase = ob * 16 + lg * 4;
  #pragma unroll
  for (int r = 0; r < 4; ++r)
    F.bs[r] = b[F.obase + r] + b[64 + F.obase + r] + b[128 + F.obase + r];
}

// ---- overlapped touch: issue 3 line-strided loads of a FUTURE tile's x.
// Consumption (sink add) MUST sit after covering compute (R14/R16 lesson).
static __device__ __forceinline__ void touch_issue(
    const float* __restrict__ x, int tile, int tid, float* tv) {
  const int n = tile / NTILE;
  const int t0 = (tile - n * NTILE) * TT;
  const float* base = x + (size_t)n * 480000 + (size_t)t0 * 25;
  #pragma unroll
  for (int j = 0; j < 3; ++j) {
    int idx = tid + (j << 9);          // 0..1535
    int c = idx / 19;                  // 19 lines (64B) per c-row
    int li = idx - c * 19;
    tv[j] = (c < 64) ? base[(size_t)c * 7500 + li * 16] : 0.f;
  }
}

// ---- x staging: 512 threads = 64 c-rows x 8 v-blocks; pure bit-op indexing.
static __device__ __forceinline__ void stage_x(
    const float* __restrict__ x, SmemU& sm, int n, int t0, int tid) {
  const int c = tid >> 3, vb = tid & 7;
  const int em = emask(c);
  const float* xr = x + (size_t)n * 480000 + (size_t)c * 7500 + (size_t)t0 * 25;
  bf16_t* xsr = &sm.xs[c * XROW];
  #pragma unroll
  for (int t = 0; t < TT; ++t) {
    bf16x4 h;
    if (vb < 6) {
      f32x4u v4 = *reinterpret_cast<const f32x4u*>(xr + t * 25 + vb * 4);
      h[0] = tobf(v4[0]); h[1] = tobf(v4[1]); h[2] = tobf(v4[2]); h[3] = tobf(v4[3]);
    } else if (vb == 6) {
      float s = xr[t * 25 + 24];
      h[0] = tobf(s); h[1] = tobf(0.f); h[2] = tobf(0.f); h[3] = tobf(0.f);
    } else {
      h[0] = tobf(0.f); h[1] = tobf(0.f); h[2] = tobf(0.f); h[3] = tobf(0.f);
    }
    *reinterpret_cast<bf16x4*>(&xsr[(((t << 5) + vb * 4) ^ em)]) = h;
  }
}

// one t, one wh: register-chained stage-A -> stage-B (R3..R24-verified mapping)
static __device__ __forceinline__ void compute_wh(
    const bf16x8* xf, const Frags& F, int wh, f32x4& acc0, f32x4& acc1) {
  acc0 = f32x4{0.f, 0.f, 0.f, 0.f};
  acc1 = f32x4{0.f, 0.f, 0.f, 0.f};
  #pragma unroll
  for (int k = 0; k < 3; ++k) {
    #pragma unroll
    for (int ch = 0; ch < 2; ++ch) {
      f32x4 zero = {0.f, 0.f, 0.f, 0.f};
      f32x4 dP = __builtin_amdgcn_mfma_f32_16x16x32_bf16(xf[ch * 2 + 0], F.afrag[k][wh], zero, 0, 0, 0);
      f32x4 dQ = __builtin_amdgcn_mfma_f32_16x16x32_bf16(xf[ch * 2 + 1], F.afrag[k][wh], zero, 0, 0, 0);
      bf16x8 zf;
      zf[0] = tobf(dP[0]); zf[1] = tobf(dP[1]); zf[2] = tobf(dP[2]); zf[3] = tobf(dP[3]);
      zf[4] = tobf(dQ[0]); zf[5] = tobf(dQ[1]); zf[6] = tobf(dQ[2]); zf[7] = tobf(dQ[3]);
      if (ch == 0)
        acc0 = __builtin_amdgcn_mfma_f32_16x16x32_bf16(F.wfrag[k * 2 + ch], zf, acc0, 0, 0, 0);
      else
        acc1 = __builtin_amdgcn_mfma_f32_16x16x32_bf16(F.wfrag[k * 2 + ch], zf, acc1, 0, 0, 0);
    }
  }
}

// ---------------------------------------------------------------------------
// K1 (templated): compute y + per-block channel partials.
// MODE 0: store y f32 to d_out NCHW (R18/R24 path).
// MODE 1: store y bf16 to ystage packed chunks -- each store instruction
//         covers 128B fully (64 lanes x 2B contiguous): zero RMW, -44MB.
// ---------------------------------------------------------------------------
template<int MODE>
__global__ __launch_bounds__(NTHR, 4) void k1_compute(
    const float* __restrict__ x, const float* __restrict__ A,
    const float* __restrict__ W, const float* __restrict__ b,
    float* __restrict__ y, bf16_t* __restrict__ ystage,
    float* __restrict__ part) {
  __shared__ __align__(16) SmemU sm;
  __shared__ float stats2[2][2][64];   // [sum|sq][t-half][o]

  const int bid = blockIdx.x;
  const int tid = threadIdx.x;
  const int lane = tid & 63;
  const int wv = tid >> 6;
  const int ob = wv & 3;
  const int th = wv >> 2;
  const int l15 = lane & 15;
  const int lg = lane >> 4;

  stage_wa(A, W, sm, tid);
  __syncthreads();
  Frags F;
  read_frags(sm, b, ob, l15, lg, F);
  __syncthreads();                 // all wa reads done before xs overwrite

  float lsum[4] = {0.f, 0.f, 0.f, 0.f}, lsq[4] = {0.f, 0.f, 0.f, 0.f};
  float sink = 0.f;

  #pragma unroll
  for (int i = 0; i < 2; ++i) {
    const int tile = bid * 2 + i;
    const int n = tile / NTILE;
    const int t0 = (tile - n * NTILE) * TT;

    stage_x(x, sm, n, t0, tid);
    __syncthreads();

    float tv[3] = {0.f, 0.f, 0.f};
    if (i == 0) touch_issue(x, tile + 1, tid, tv);   // warm tile 1 under compute

    float* yb = y + (size_t)n * 480000 + (size_t)t0 * 25;

    #pragma unroll 2
    for (int tl = 0; tl < 6; ++tl) {
      const int t = th * 6 + tl;
      bf16x8 xf[4];
      #pragma unroll
      for (int q = 0; q < 4; ++q)
        xf[q] = *reinterpret_cast<const bf16x8*>(sm.xs + F.fK[q] + ((t << 5) ^ F.fS5[q]));
      #pragma unroll
      for (int wh = 0; wh < 2; ++wh) {
        f32x4 acc0, acc1;
        compute_wh(xf, F, wh, acc0, acc1);
        const int w = wh ? 16 + l15 : l15;
        if (w < V_) {
          #pragma unroll
          for (int r = 0; r < 4; ++r) {
            float val = acc0[r] + acc1[r] + F.bs[r];
            lsum[r] += val;
            lsq[r] += val * val;
          }
        }
        if constexpr (MODE == 0) {
          if (w < V_) {
            #pragma unroll
            for (int r = 0; r < 4; ++r)
              yb[(size_t)(F.obase + r) * 7500 + t * 25 + w] =
                  acc0[r] + acc1[r] + F.bs[r];
          }
        } else {
          // packed chunk: ((n*300+tG)*4 + ob)*512 + wh*256 + r*64 + lane
          bf16_t* cb = ystage + (size_t)(n * 300 + t0 + t) * 2048 +
                       ob * 512 + wh * 256 + lane;
          #pragma unroll
          for (int r = 0; r < 4; ++r)
            cb[r * 64] = tobf(acc0[r] + acc1[r] + F.bs[r]);   // all lanes: full 128B/instr
        }
      }
    }
    sink += tv[0] + tv[1] + tv[2];   // touch consumption AFTER compute
    __syncthreads();   // all xs reads done before next tile's stage_x
  }
  asm volatile("" :: "v"(sink));     // keep touches alive (rule #17)

  #pragma unroll
  for (int d = 1; d < 16; d <<= 1) {
    #pragma unroll
    for (int r = 0; r < 4; ++r) {
      lsum[r] += __shfl_xor(lsum[r], d);
      lsq[r]  += __shfl_xor(lsq[r], d);
    }
  }
  if (l15 == 0) {
    #pragma unroll
    for (int r = 0; r < 4; ++r) {
      stats2[0][th][F.obase + r] = lsum[r];
      stats2[1][th][F.obase + r] = lsq[r];
    }
  }
  __syncthreads();
  if (tid < 128)
    part[(size_t)bid * 128 + tid] =
        stats2[tid >> 6][0][tid & 63] + stats2[tid >> 6][1][tid & 63];
}

// ---------------------------------------------------------------------------
// K2: reduce per-block partials -> per-channel scale/shift
// ---------------------------------------------------------------------------
__global__ __launch_bounds__(256) void k2_stats(
    const float* __restrict__ part,
    const float* __restrict__ gamma, const float* __restrict__ beta,
    float* __restrict__ ss) {
  const int o = blockIdx.x;
  const int tid = threadIdx.x;
  double s = 0.0, q = 0.0;
  for (int i = tid; i < NPERS; i += 256) {
    s += (double)part[(size_t)i * 128 + o];
    q += (double)part[(size_t)i * 128 + 64 + o];
  }
  __shared__ double sd[256], qd[256];
  sd[tid] = s; qd[tid] = q;
  __syncthreads();
  for (int step = 128; step > 0; step >>= 1) {
    if (tid < step) { sd[tid] += sd[tid + step]; qd[tid] += qd[tid + step]; }
    __syncthreads();
  }
  if (tid == 0) {
    const double cnt = 480000.0;
    double mean = sd[0] / cnt;
    double var = qd[0] / cnt - mean * mean;
    float inv = rsqrtf((float)var + EPS_);
    float sc = gamma[o] * inv;
    float sh = beta[o] - (float)mean * sc;
    ss[2 * o] = sc;
    ss[2 * o + 1] = sh;
  }
}

// ---------------------------------------------------------------------------
// K3 (MODE 0 fallback): in-place finish on d_out. 16B-aligned vector nt.
// ---------------------------------------------------------------------------
__global__ __launch_bounds__(256) void k3_finish(
    const float* __restrict__ x, const float* __restrict__ ss,
    float* __restrict__ y) {
  const int p = blockIdx.x;       // 0..4095 = n*64 + c
  const int c = p & 63;
  const float sc = ss[2 * c];
  const float sh = ss[2 * c + 1];
  const f32x4* xv = reinterpret_cast<const f32x4*>(x + (size_t)p * 7500);
  f32x4* yv = reinterpret_cast<f32x4*>(y + (size_t)p * 7500);
  for (int i = threadIdx.x; i < 1875; i += 256) {
    f32x4 a = yv[i];
    f32x4 b4 = xv[i];
    f32x4 o;
    o[0] = fmaxf(sc * a[0] + sh + b4[0], 0.f);
    o[1] = fmaxf(sc * a[1] + sh + b4[1], 0.f);
    o[2] = fmaxf(sc * a[2] + sh + b4[2], 0.f);
    o[3] = fmaxf(sc * a[3] + sh + b4[3], 0.f);
    __builtin_nontemporal_store(o, yv + i);
  }
}

// ---------------------------------------------------------------------------
// K3 (MODE 1): one block per (n,o) plane. Gather this plane's 300x32 bf16
// from ystage into LDS (L3 hits), then linear pass: x read + BN + residual
// + relu -> 16B-aligned coalesced nt stores to out.
// ---------------------------------------------------------------------------
__global__ __launch_bounds__(256) void k3_finish_ws(
    const float* __restrict__ x, const bf16_t* __restrict__ ystage,
    const float* __restrict__ ss, float* __restrict__ out) {
  __shared__ bf16_t ys[300 * 32];   // 19.2KB
  const int p = blockIdx.x;         // n*64 + o
  const int n = p >> 6, o = p & 63;
  const int ob = o >> 4, lg = (o >> 2) & 3, r = o & 3;
  const float sc = ss[2 * o], sh = ss[2 * o + 1];

  const bf16_t* ybase = ystage + (size_t)n * 300 * 2048 + ob * 512 + r * 64 + lg * 16;
  for (int idx = threadIdx.x; idx < 300 * 32; idx += 256) {
    int t = idx >> 5, w = idx & 31;
    ys[idx] = ybase[(size_t)t * 2048 + (w >> 4) * 256 + (w & 15)];
  }
  __syncthreads();

  const float* xp = x + (size_t)p * 7500;
  float* op = out + (size_t)p * 7500;
  for (int i = threadIdx.x; i < 1875; i += 256) {
    int e = 4 * i;
    f32x4u xv4 = *reinterpret_cast<const f32x4u*>(xp + e);
    f32x4 ov;
    #pragma unroll
    for (int j = 0; j < 4; ++j) {
      int ej = e + j;
      int t = ej / 25;              // const divide -> magic mul
      int w = ej - t * 25;
      float yv = (float)ys[t * 32 + w];
      ov[j] = fmaxf(sc * yv + sh + xv4[j], 0.f);
    }
    __builtin_nontemporal_store(ov, reinterpret_cast<f32x4*>(op + e));  // 16B-aligned
  }
}

extern "C" void kernel_launch(void* const* d_in, const int* in_sizes, int n_in,
                              void* d_out, int out_size, void* d_ws, size_t ws_size,
                              hipStream_t stream) {
  const float* x     = (const float*)d_in[0];
  const float* A     = (const float*)d_in[1];
  const float* W     = (const float*)d_in[2];
  const float* b     = (const float*)d_in[3];
  const float* gamma = (const float*)d_in[4];
  const float* beta  = (const float*)d_in[5];
  float* out = (float*)d_out;

  const size_t need = YELEMS * 2 + (size_t)NPERS * 128 * 4 + 512;
  if (ws_size >= need) {
    // ystage path: bf16 packed y in d_ws (78.6MB), full-line k1 stores
    bf16_t* ystage = (bf16_t*)d_ws;
    float* part = (float*)((char*)d_ws + YELEMS * 2);
    float* ss   = part + (size_t)NPERS * 128;
    k1_compute<1><<<NPERS, NTHR, 0, stream>>>(x, A, W, b, nullptr, ystage, part);
    k2_stats<<<64, 256, 0, stream>>>(part, gamma, beta, ss);
    k3_finish_ws<<<4096, 256, 0, stream>>>(x, ystage, ss, out);
  } else {
    // R24 fallback: f32 y staged in d_out, in-place finish
    float* part = (float*)d_ws;
    float* ss   = part + (size_t)NPERS * 128;
    k1_compute<0><<<NPERS, NTHR, 0, stream>>>(x, A, W, b, out, nullptr, part);
    k2_stats<<<64, 256, 0, stream>>>(part, gamma, beta, ss);
    k3_finish<<<4096, 256, 0, stream>>>(x, ss, out);
  }
}